// Round 9
// baseline (255.599 us; speedup 1.0000x reference)
//
#include <hip/hip_runtime.h>
#include <hip/hip_bf16.h>
#include <stdint.h>

typedef __attribute__((ext_vector_type(4))) int i32x4;     // i8 MFMA A/B/C: 4 dwords

#define K_TOT 4096
#define N_TOT 4096

// ---------------- fused prepass: x-quant (blocks < nqb) + w-pack (rest) -------------
__global__ __launch_bounds__(512) void prep_kernel(const float4* __restrict__ x4,
                                                   unsigned int* __restrict__ xq_dw,
                                                   float* __restrict__ s_row,
                                                   int* __restrict__ qsum_row,
                                                   const int4* __restrict__ wq,
                                                   unsigned int* __restrict__ w8,
                                                   int nqb) {
    const int wave = threadIdx.x >> 6, lane = threadIdx.x & 63;
    if ((int)blockIdx.x < nqb) {
        const long row = (long)blockIdx.x * 8 + wave;
        const float4* xr = x4 + row * (K_TOT / 4);
        float4 v[16];
        float amax = 0.f;
#pragma unroll
        for (int i = 0; i < 16; ++i) {
            v[i] = xr[lane + i * 64];
            amax = fmaxf(amax, fmaxf(fmaxf(fabsf(v[i].x), fabsf(v[i].y)),
                                     fmaxf(fabsf(v[i].z), fabsf(v[i].w))));
        }
#pragma unroll
        for (int off = 32; off; off >>= 1) amax = fmaxf(amax, __shfl_xor(amax, off));
        amax = fmaxf(amax, 1e-30f);
        const float inv = 127.0f / amax;
        int qsum = 0;
        unsigned int* out = xq_dw + row * (K_TOT / 4);
#pragma unroll
        for (int i = 0; i < 16; ++i) {
            int q0 = (int)rintf(v[i].x * inv), q1 = (int)rintf(v[i].y * inv);
            int q2 = (int)rintf(v[i].z * inv), q3 = (int)rintf(v[i].w * inv);
            qsum += q0 + q1 + q2 + q3;
            out[lane + i * 64] = (unsigned int)(q0 & 255) | ((unsigned int)(q1 & 255) << 8) |
                                 ((unsigned int)(q2 & 255) << 16) | ((unsigned int)(q3 & 255) << 24);
        }
#pragma unroll
        for (int off = 32; off; off >>= 1) qsum += __shfl_xor(qsum, off);
        if (lane == 0) { s_row[row] = amax / 127.0f; qsum_row[row] = qsum; }
    } else {
        const long o = (long)((int)blockIdx.x - nqb) * 8 + wave;
        const int4* src = wq + o * (K_TOT / 4);
        unsigned int* dst = w8 + o * (K_TOT / 4);
#pragma unroll
        for (int i = 0; i < 16; ++i) {
            int4 q = src[lane + i * 64];
            dst[lane + i * 64] =
                (unsigned int)((q.x - 128) & 255) | ((unsigned int)((q.y - 128) & 255) << 8) |
                ((unsigned int)((q.z - 128) & 255) << 16) | ((unsigned int)((q.w - 128) & 255) << 24);
        }
    }
}

// ================= 256x256 i8 GEMM, reg-pipelined, 3-deep LDS =======================
// D[M,N](i32) = Xq[M,K](i8) * W8[N,K](i8)^T via mfma_i32_16x16x64_i8.
// 8 waves (2M x 4N), wave tile 128x64; K-tile = 64; LDS = 3 x 32KiB (A16K+B16K).
// KEY: frags(t+1) are ds_read into the ALTERNATE register set while MFMA(frags t)
// runs -> the 12 ds_read_b128 and 32 MFMA are independent, compiler interleaves
// (per-wave overlap of the two binding resources instead of barrier-locked serial).
// Per K-tile: 1 barrier, 4 gload_lds (stage t+3), 12 ds_read, 32 MFMA, counted
// vmcnt(4) BEFORE the next barrier (per-wave drain + barrier = all-wave guarantee).
// Ledger (steady state, outstanding before STEP t = [t+2(4)]):
//   BAR | stage(t+3)->lds[t%3] (8 out) | read frags(t+1)<-lds[(t+1)%3] | MFMA(t)
//   | lgkmcnt(0) (reads done pre-barrier) | vmcnt(4) retires t+2 -> next reads safe.
// Swizzle: LDS dest linear (global_load_lds), 16B-chunk XOR ((row>>1)&3) on global
// source and identically on ds_read -> <=2-way conflicts (free).

struct Frag { i32x4 a[8]; i32x4 b[4]; };

#define BAR() __builtin_amdgcn_s_barrier()
#define LGKM0() asm volatile("s_waitcnt lgkmcnt(0)" ::: "memory")
#define VMCNT8() asm volatile("s_waitcnt vmcnt(8)" ::: "memory")
#define VMCNT4() asm volatile("s_waitcnt vmcnt(4)" ::: "memory")
#define VMCNT0() asm volatile("s_waitcnt vmcnt(0)" ::: "memory")
#define SCHEDB() __builtin_amdgcn_sched_barrier(0)
#define PRIO1() __builtin_amdgcn_s_setprio(1)
#define PRIO0() __builtin_amdgcn_s_setprio(0)

__launch_bounds__(512, 1)
__global__ void gemm256_i8_kernel(const char* __restrict__ Aq,   // [M][K] i8
                                  const char* __restrict__ Bq,   // [N][K] i8
                                  const float* __restrict__ s_row,
                                  const int* __restrict__ qsum_row,
                                  const float* __restrict__ scale,
                                  const int* __restrict__ zp,
                                  const float* __restrict__ bias,
                                  float* __restrict__ C) {
    __shared__ __align__(16) char lds[3][2][16384];   // [buf][A|B][256rows x 64B] 96 KiB

    const int nbn = N_TOT / 256;                      // 16
    int bid = blockIdx.x;
    const int nwg = gridDim.x;
    if ((nwg & 7) == 0) {                             // T1: bijective XCD swizzle
        const int cpx = nwg >> 3;
        bid = (bid & 7) * cpx + (bid >> 3);
    }
    const int bm = bid / nbn, bn = bid % nbn;

    const int tid = threadIdx.x;
    const int w = tid >> 6, lane = tid & 63;
    const int wr = w >> 2, wc = w & 3;                // 2x4 wave grid
    const int fr = lane & 15, kg = lane >> 4;         // fragment row / k-group
    const int brb = (wc >> 1) * 128 + (wc & 1) * 64;  // B row base (0..255)
    const int sw = (fr >> 1) & 3;                     // read-side chunk swizzle

    const long a_row0 = (long)bm * 256;
    const long b_row0 = (long)bn * 256;

    i32x4 acc[8][4] = {};
    Frag fx, fy;

    // stage one K-tile (A 16KB + B 16KB): 4 global_load_lds per thread.
    auto stage_tile = [&](int t, char (*L)[16384]) {
        const int row = w * 16 + (lane >> 2);               // row within 128-row half
#pragma unroll
        for (int half = 0; half < 2; ++half) {
            const int c = (lane & 3) ^ (((half * 128 + row) >> 1) & 3);
            {
                char* lb = &L[0][half * 8192 + w * 1024];
                const char* g = Aq + (a_row0 + half * 128 + row) * (long)K_TOT +
                                (long)t * 64 + c * 16;
                __builtin_amdgcn_global_load_lds(
                    (const __attribute__((address_space(1))) void*)g,
                    (__attribute__((address_space(3))) void*)lb, 16, 0, 0);
            }
            {
                char* lb = &L[1][half * 8192 + w * 1024];
                const char* g = Bq + (b_row0 + half * 128 + row) * (long)K_TOT +
                                (long)t * 64 + c * 16;
                __builtin_amdgcn_global_load_lds(
                    (const __attribute__((address_space(1))) void*)g,
                    (__attribute__((address_space(3))) void*)lb, 16, 0, 0);
            }
        }
    };

    auto read_frags = [&](Frag& f, const char (*L)[16384]) {
        const char* Ab = &L[0][0];
        const char* Bb = &L[1][0];
#pragma unroll
        for (int m = 0; m < 8; ++m)
            f.a[m] = *(const i32x4*)(Ab + (wr * 128 + m * 16 + fr) * 64 + ((kg ^ sw) << 4));
#pragma unroll
        for (int n = 0; n < 4; ++n)
            f.b[n] = *(const i32x4*)(Bb + (brb + n * 16 + fr) * 64 + ((kg ^ sw) << 4));
    };

    auto mfma32 = [&](Frag& f) {
        PRIO1();
#pragma unroll
        for (int m = 0; m < 8; ++m)
#pragma unroll
            for (int n = 0; n < 4; ++n)
                acc[m][n] = __builtin_amdgcn_mfma_i32_16x16x64_i8(f.a[m], f.b[n], acc[m][n], 0, 0, 0);
        PRIO0();
    };

#define STEP(T, SB, RB, CUR, NXT, DO_STAGE, VM) \
    BAR(); \
    if (DO_STAGE) stage_tile((T) + 3, lds[SB]); \
    read_frags(NXT, lds[RB]); \
    mfma32(CUR); \
    LGKM0(); SCHEDB(); \
    VM()

    // prologue: stage tiles 0,1,2; drain 0 (all-wave via VMCNT+BAR); read frags(0);
    // then drain 1 (pre-barrier of STEP 0) so STEP 0's reads of tile 1 are safe.
    stage_tile(0, lds[0]); stage_tile(1, lds[1]); stage_tile(2, lds[2]);
    VMCNT8();
    BAR();
    read_frags(fx, lds[0]);
    LGKM0(); SCHEDB();
    VMCNT4();

    // main: 64 K-tiles; t=0..59 in a 6-unrolled loop (buf=t%3, parity fx/fy), tail 60..63
#pragma unroll 1
    for (int it = 0; it < 10; ++it) {
        const int t = it * 6;
        STEP(t + 0, 0, 1, fx, fy, true, VMCNT4);
        STEP(t + 1, 1, 2, fy, fx, true, VMCNT4);
        STEP(t + 2, 2, 0, fx, fy, true, VMCNT4);
        STEP(t + 3, 0, 1, fy, fx, true, VMCNT4);
        STEP(t + 4, 1, 2, fx, fy, true, VMCNT4);
        STEP(t + 5, 2, 0, fy, fx, true, VMCNT4);
    }
    STEP(60, 0, 1, fx, fy, true, VMCNT4);    // stage(63)->buf0; retire 62
    STEP(61, 1, 2, fy, fx, false, VMCNT0);   // read 62; retire 63
    STEP(62, 2, 0, fx, fy, false, VMCNT0);   // read 63
    mfma32(fy);                               // tile 63
#undef STEP

    // epilogue: y = (scale[col]*s[row]) * (acc + (128-zp[col])*qsum[row]) + bias[col]
    float scs[4], c1s[4], bbs[4]; int cols[4];
#pragma unroll
    for (int n = 0; n < 4; ++n) {
        cols[n] = (int)b_row0 + brb + n * 16 + fr;
        scs[n] = scale[cols[n]];
        c1s[n] = (float)(128 - zp[cols[n]]);
        bbs[n] = bias[cols[n]];
    }
#pragma unroll
    for (int m = 0; m < 8; ++m) {
#pragma unroll
        for (int j = 0; j < 4; ++j) {
            const long r = a_row0 + wr * 128 + m * 16 + kg * 4 + j;
            const float sr = s_row[r];
            const float qs = (float)qsum_row[r];
#pragma unroll
            for (int n = 0; n < 4; ++n)
                C[r * N_TOT + cols[n]] = ((float)acc[m][n][j] + c1s[n] * qs) * (scs[n] * sr) + bbs[n];
        }
    }
}

// ---------------- fallback (ws too small / M%256!=0): fp32 tiled GEMM ----------------
__global__ void fallback_kernel(const float* __restrict__ x, const int* __restrict__ wq,
                                const int* __restrict__ zp, const float* __restrict__ sc,
                                const float* __restrict__ bs, float* __restrict__ y) {
    __shared__ float xs[32][33];
    __shared__ float ws[32][33];
    int bm = blockIdx.y, bn = blockIdx.x;
    int tid = threadIdx.x;
    int r = tid >> 5, c = tid & 31;
    float acc[4] = {0.f, 0.f, 0.f, 0.f};
    for (int k0 = 0; k0 < K_TOT; k0 += 32) {
        for (int t = tid; t < 32 * 32; t += 256) {
            int rr = t >> 5, cc = t & 31;
            xs[rr][cc] = x[(long)(bm * 32 + rr) * K_TOT + k0 + cc];
            int o = bn * 32 + rr;
            ws[rr][cc] = (float)(wq[(long)o * K_TOT + k0 + cc] - zp[o]);
        }
        __syncthreads();
#pragma unroll
        for (int kk = 0; kk < 32; ++kk) {
            float wv = ws[c][kk];
#pragma unroll
            for (int j = 0; j < 4; ++j) acc[j] += xs[r + 8 * j][kk] * wv;
        }
        __syncthreads();
    }
    int o = bn * 32 + c;
    float s = sc[o], b = bs[o];
#pragma unroll
    for (int j = 0; j < 4; ++j)
        y[(long)(bm * 32 + r + 8 * j) * N_TOT + o] = acc[j] * s + b;
}

extern "C" void kernel_launch(void* const* d_in, const int* in_sizes, int n_in,
                              void* d_out, int out_size, void* d_ws, size_t ws_size,
                              hipStream_t stream) {
    const float* x = (const float*)d_in[0];
    const int* wq = (const int*)d_in[1];
    const int* zp = (const int*)d_in[2];
    const float* sc = (const float*)d_in[3];
    const float* bs = (const float*)d_in[4];
    float* y = (float*)d_out;

    const long M = (long)in_sizes[0] / K_TOT;   // 8192

    size_t xq_bytes = (size_t)M * K_TOT;              // 33.5 MB
    size_t w8_bytes = (size_t)N_TOT * K_TOT;          // 16.8 MB
    size_t s_bytes = (size_t)M * 4;
    size_t q_bytes = (size_t)M * 4;
    size_t need = xq_bytes + w8_bytes + s_bytes + q_bytes + 256;

    if (ws_size >= need && (M & 255) == 0) {
        char* p = (char*)d_ws;
        char* xq = p;                       p += xq_bytes;
        char* w8 = p;                       p += w8_bytes;
        float* s_row = (float*)p;           p += s_bytes;
        int* qsum_row = (int*)p;

        const int nqb = (int)(M / 8);                       // 1024 quant blocks
        const int npb = N_TOT / 8;                          // 512 pack blocks
        prep_kernel<<<nqb + npb, 512, 0, stream>>>(
            (const float4*)x, (unsigned int*)xq, s_row, qsum_row,
            (const int4*)wq, (unsigned int*)w8, nqb);

        dim3 grid((unsigned)((M / 256) * (N_TOT / 256)));   // 512
        gemm256_i8_kernel<<<grid, 512, 0, stream>>>(
            xq, w8, s_row, qsum_row, sc, zp, bs, y);
    } else {
        dim3 grid(N_TOT / 32, (unsigned)(M / 32));
        fallback_kernel<<<grid, 256, 0, stream>>>(x, wq, zp, sc, bs, y);
    }
}

// Round 10
// 190.105 us; speedup vs baseline: 1.3445x; 1.3445x over previous
//
#include <hip/hip_runtime.h>
#include <hip/hip_bf16.h>
#include <stdint.h>

typedef __attribute__((ext_vector_type(4))) int i32x4;     // i8 MFMA A/B/C: 4 dwords

#define K_TOT 4096
#define N_TOT 4096

// ---------------- fused prepass: x-quant (blocks < nqb) + w-pack (rest) -------------
__global__ __launch_bounds__(512) void prep_kernel(const float4* __restrict__ x4,
                                                   unsigned int* __restrict__ xq_dw,
                                                   float* __restrict__ s_row,
                                                   int* __restrict__ qsum_row,
                                                   const int4* __restrict__ wq,
                                                   unsigned int* __restrict__ w8,
                                                   int nqb) {
    const int wave = threadIdx.x >> 6, lane = threadIdx.x & 63;
    if ((int)blockIdx.x < nqb) {
        const long row = (long)blockIdx.x * 8 + wave;
        const float4* xr = x4 + row * (K_TOT / 4);
        float4 v[16];
        float amax = 0.f;
#pragma unroll
        for (int i = 0; i < 16; ++i) {
            v[i] = xr[lane + i * 64];
            amax = fmaxf(amax, fmaxf(fmaxf(fabsf(v[i].x), fabsf(v[i].y)),
                                     fmaxf(fabsf(v[i].z), fabsf(v[i].w))));
        }
#pragma unroll
        for (int off = 32; off; off >>= 1) amax = fmaxf(amax, __shfl_xor(amax, off));
        amax = fmaxf(amax, 1e-30f);
        const float inv = 127.0f / amax;
        int qsum = 0;
        unsigned int* out = xq_dw + row * (K_TOT / 4);
#pragma unroll
        for (int i = 0; i < 16; ++i) {
            int q0 = (int)rintf(v[i].x * inv), q1 = (int)rintf(v[i].y * inv);
            int q2 = (int)rintf(v[i].z * inv), q3 = (int)rintf(v[i].w * inv);
            qsum += q0 + q1 + q2 + q3;
            out[lane + i * 64] = (unsigned int)(q0 & 255) | ((unsigned int)(q1 & 255) << 8) |
                                 ((unsigned int)(q2 & 255) << 16) | ((unsigned int)(q3 & 255) << 24);
        }
#pragma unroll
        for (int off = 32; off; off >>= 1) qsum += __shfl_xor(qsum, off);
        if (lane == 0) { s_row[row] = amax / 127.0f; qsum_row[row] = qsum; }
    } else {
        const long o = (long)((int)blockIdx.x - nqb) * 8 + wave;
        const int4* src = wq + o * (K_TOT / 4);
        unsigned int* dst = w8 + o * (K_TOT / 4);
#pragma unroll
        for (int i = 0; i < 16; ++i) {
            int4 q = src[lane + i * 64];
            dst[lane + i * 64] =
                (unsigned int)((q.x - 128) & 255) | ((unsigned int)((q.y - 128) & 255) << 8) |
                ((unsigned int)((q.z - 128) & 255) << 16) | ((unsigned int)((q.w - 128) & 255) << 24);
        }
    }
}

// ================= 256x256 4-phase i8 GEMM, relaxed intra-phase lockstep ============
// D[M,N](i32) = Xq[M,K](i8) * W8[N,K](i8)^T via mfma_i32_16x16x64_i8 (K=64/instr).
// 8 waves (2M x 4N), per-wave 128x64; BK=64, 2 K-tiles/iter, 64 KiB LDS dbuf.
// R10 change vs R6: ONE barrier per phase (at phase end); no forced lgkmcnt(0) --
// the compiler's counted lgkmcnt waits (register dataflow: MFMA consumes ds_read
// results) both guarantee correctness and let waves skew within a phase so one
// wave's MFMA burst overlaps another's LDS-read burst (setprio arbitrates).
// WAR proof: a wave past phase-end BAR has issued its MFMAs, which required its
// ds_reads complete -> any later-phase stage() overwrite is safe for all waves.
// Ledger unchanged (outstanding gload_lds): pro leaves t1.B(2); P1 +t1.A(2);
// P2 +t2.B(2), vmcnt(2) keeps t2.B; P3 +t2.A(2); P4 +t3.B(2), vmcnt(2) keeps t3.B.
// Swizzle: LDS dest linear (global_load_lds), 16B-chunk XOR ((row>>1)&3) on global
// source and identically on ds_read -> <=2-way conflicts (free).

template<int MH>
__device__ __forceinline__ void read_a8(i32x4 (&a)[4], const char* Ab, int wr, int fr, int kg) {
    const int sw = (fr >> 1) & 3;
#pragma unroll
    for (int mi = 0; mi < 4; ++mi) {
        const int row = wr * 128 + (MH * 4 + mi) * 16 + fr;
        a[mi] = *(const i32x4*)(Ab + row * 64 + ((kg ^ sw) << 4));
    }
}

template<int NH>
__device__ __forceinline__ void read_b8(i32x4 (&b)[2], const char* Bb, int rb, int fr, int kg) {
    const int sw = (fr >> 1) & 3;
#pragma unroll
    for (int ni = 0; ni < 2; ++ni) {
        const int row = rb + (NH * 2 + ni) * 16 + fr;
        b[ni] = *(const i32x4*)(Bb + row * 64 + ((kg ^ sw) << 4));
    }
}

template<int MH, int NH>
__device__ __forceinline__ void mfma8(i32x4 (&acc)[8][4], i32x4 (&a)[4], i32x4 (&b)[2]) {
#pragma unroll
    for (int mi = 0; mi < 4; ++mi)
#pragma unroll
        for (int ni = 0; ni < 2; ++ni)
            acc[MH * 4 + mi][NH * 2 + ni] = __builtin_amdgcn_mfma_i32_16x16x64_i8(
                a[mi], b[ni], acc[MH * 4 + mi][NH * 2 + ni], 0, 0, 0);
}

#define BAR() __builtin_amdgcn_s_barrier()
#define VMCNT2() asm volatile("s_waitcnt vmcnt(2)" ::: "memory")
#define VMCNT0() asm volatile("s_waitcnt vmcnt(0)" ::: "memory")
#define PRIO1() __builtin_amdgcn_s_setprio(1)
#define PRIO0() __builtin_amdgcn_s_setprio(0)

__launch_bounds__(512, 2)
__global__ void gemm256_i8_kernel(const char* __restrict__ Aq,   // [M][K] i8
                                  const char* __restrict__ Bq,   // [N][K] i8
                                  const float* __restrict__ s_row,
                                  const int* __restrict__ qsum_row,
                                  const float* __restrict__ scale,
                                  const int* __restrict__ zp,
                                  const float* __restrict__ bias,
                                  float* __restrict__ C) {
    __shared__ __align__(16) char lds[4][256 * 64];   // [buf*2+mat][row*64+byte] 64 KiB

    const int nbn = N_TOT / 256;                      // 16
    int bid = blockIdx.x;
    const int nwg = gridDim.x;
    if ((nwg & 7) == 0) {                             // T1: bijective XCD swizzle
        const int cpx = nwg >> 3;
        bid = (bid & 7) * cpx + (bid >> 3);
    }
    const int bm = bid / nbn, bn = bid % nbn;

    const int tid = threadIdx.x;
    const int w = tid >> 6, lane = tid & 63;
    const int wr = w >> 2, wc = w & 3;                // 2x4 wave grid
    const int fr = lane & 15, kg = lane >> 4;         // fragment row / k-group
    const int brb = (wc >> 1) * 128 + (wc & 1) * 64;  // B row base (within 256-row tile)

    const long a_row0 = (long)bm * 256;
    const long b_row0 = (long)bn * 256;

    i32x4 acc[8][4] = {};
    i32x4 afr[4], b0[2], b1[2];

    // stage one half-tile (128 rows x 64 B): 1 global_load_lds per thread.
    auto stage = [&](int t, int mat, int half) {
        const char* G = (mat == 0) ? Aq : Bq;
        const long row0 = ((mat == 0) ? a_row0 : b_row0) + half * 128;
        char* lb = &lds[(t & 1) * 2 + mat][half * 8192 + w * 1024];
        const int row = w * 16 + (lane >> 2);               // row within half
        const int c = (lane & 3) ^ (((half * 128 + row) >> 1) & 3);  // pre-swizzled 16B chunk
        const char* g = G + (row0 + row) * K_TOT + (long)t * 64 + c * 16;
        __builtin_amdgcn_global_load_lds(
            (const __attribute__((address_space(1))) void*)g,
            (__attribute__((address_space(3))) void*)lb, 16, 0, 0);
    };

    const char* Ab0 = &lds[0][0];
    const char* Bb0 = &lds[1][0];
    const char* Ab1 = &lds[2][0];
    const char* Bb1 = &lds[3][0];

    // prologue: t0 fully + t1.B; drain t0 (leave t1.B = 2 outstanding).
    stage(0, 0, 0); stage(0, 0, 1); stage(0, 1, 0); stage(0, 1, 1);
    stage(1, 1, 0); stage(1, 1, 1);
    VMCNT2();
    BAR();

    const int NIT = K_TOT / 128;                      // 32 iters, 64 K-tiles
#pragma unroll 1
    for (int it = 0; it < NIT; ++it) {
        const bool nl = (it != NIT - 1);
        const int t1 = 2 * it + 1, t2 = 2 * it + 2, t3 = 2 * it + 3;

        // ---- Ph1 (buf0, q(0,*)): read a0,b0,b1 | stage t1.A | MFMA ----
        read_a8<0>(afr, Ab0, wr, fr, kg);
        read_b8<0>(b0, Bb0, brb, fr, kg);
        read_b8<1>(b1, Bb0, brb, fr, kg);
        stage(t1, 0, 0); stage(t1, 0, 1);
        PRIO1(); mfma8<0, 0>(acc, afr, b0); mfma8<0, 1>(acc, afr, b1); PRIO0();
        BAR();
        // ---- Ph2 (buf0, q(1,*)): read a1 | stage t2.B | MFMA | drain t1 ----
        read_a8<1>(afr, Ab0, wr, fr, kg);
        if (nl) { stage(t2, 1, 0); stage(t2, 1, 1); }
        PRIO1(); mfma8<1, 1>(acc, afr, b1); mfma8<1, 0>(acc, afr, b0); PRIO0();
        if (nl) { VMCNT2(); } else { VMCNT0(); }      // retires t1.B + t1.A
        BAR();
        // ---- Ph3 (buf1, q(0,*)): read a0,b0,b1 | stage t2.A | MFMA ----
        read_a8<0>(afr, Ab1, wr, fr, kg);
        read_b8<0>(b0, Bb1, brb, fr, kg);
        read_b8<1>(b1, Bb1, brb, fr, kg);
        if (nl) { stage(t2, 0, 0); stage(t2, 0, 1); }
        PRIO1(); mfma8<0, 0>(acc, afr, b0); mfma8<0, 1>(acc, afr, b1); PRIO0();
        BAR();
        // ---- Ph4 (buf1, q(1,*)): read a1 | stage t3.B | MFMA | drain t2 ----
        read_a8<1>(afr, Ab1, wr, fr, kg);
        if (nl) { stage(t3, 1, 0); stage(t3, 1, 1); }
        PRIO1(); mfma8<1, 1>(acc, afr, b1); mfma8<1, 0>(acc, afr, b0); PRIO0();
        if (nl) { VMCNT2(); }                          // retires t2.B + t2.A
        BAR();
    }

    // epilogue: y = (scale[col]*s[row]) * (acc + (128-zp[col])*qsum[row]) + bias[col]
    float scs[4], c1s[4], bbs[4]; int cols[4];
#pragma unroll
    for (int n = 0; n < 4; ++n) {
        cols[n] = (int)b_row0 + wc * 64 + n * 16 + fr;
        scs[n] = scale[cols[n]];
        c1s[n] = (float)(128 - zp[cols[n]]);
        bbs[n] = bias[cols[n]];
    }
#pragma unroll
    for (int m = 0; m < 8; ++m) {
#pragma unroll
        for (int j = 0; j < 4; ++j) {
            const long r = a_row0 + wr * 128 + m * 16 + kg * 4 + j;
            const float sr = s_row[r];
            const float qs = (float)qsum_row[r];
#pragma unroll
            for (int n = 0; n < 4; ++n)
                C[r * N_TOT + cols[n]] = ((float)acc[m][n][j] + c1s[n] * qs) * (scs[n] * sr) + bbs[n];
        }
    }
}

// ---------------- fallback (ws too small / M%256!=0): fp32 tiled GEMM ----------------
__global__ void fallback_kernel(const float* __restrict__ x, const int* __restrict__ wq,
                                const int* __restrict__ zp, const float* __restrict__ sc,
                                const float* __restrict__ bs, float* __restrict__ y) {
    __shared__ float xs[32][33];
    __shared__ float ws[32][33];
    int bm = blockIdx.y, bn = blockIdx.x;
    int tid = threadIdx.x;
    int r = tid >> 5, c = tid & 31;
    float acc[4] = {0.f, 0.f, 0.f, 0.f};
    for (int k0 = 0; k0 < K_TOT; k0 += 32) {
        for (int t = tid; t < 32 * 32; t += 256) {
            int rr = t >> 5, cc = t & 31;
            xs[rr][cc] = x[(long)(bm * 32 + rr) * K_TOT + k0 + cc];
            int o = bn * 32 + rr;
            ws[rr][cc] = (float)(wq[(long)o * K_TOT + k0 + cc] - zp[o]);
        }
        __syncthreads();
#pragma unroll
        for (int kk = 0; kk < 32; ++kk) {
            float wv = ws[c][kk];
#pragma unroll
            for (int j = 0; j < 4; ++j) acc[j] += xs[r + 8 * j][kk] * wv;
        }
        __syncthreads();
    }
    int o = bn * 32 + c;
    float s = sc[o], b = bs[o];
#pragma unroll
    for (int j = 0; j < 4; ++j)
        y[(long)(bm * 32 + r + 8 * j) * N_TOT + o] = acc[j] * s + b;
}

extern "C" void kernel_launch(void* const* d_in, const int* in_sizes, int n_in,
                              void* d_out, int out_size, void* d_ws, size_t ws_size,
                              hipStream_t stream) {
    const float* x = (const float*)d_in[0];
    const int* wq = (const int*)d_in[1];
    const int* zp = (const int*)d_in[2];
    const float* sc = (const float*)d_in[3];
    const float* bs = (const float*)d_in[4];
    float* y = (float*)d_out;

    const long M = (long)in_sizes[0] / K_TOT;   // 8192

    size_t xq_bytes = (size_t)M * K_TOT;              // 33.5 MB
    size_t w8_bytes = (size_t)N_TOT * K_TOT;          // 16.8 MB
    size_t s_bytes = (size_t)M * 4;
    size_t q_bytes = (size_t)M * 4;
    size_t need = xq_bytes + w8_bytes + s_bytes + q_bytes + 256;

    if (ws_size >= need && (M & 255) == 0) {
        char* p = (char*)d_ws;
        char* xq = p;                       p += xq_bytes;
        char* w8 = p;                       p += w8_bytes;
        float* s_row = (float*)p;           p += s_bytes;
        int* qsum_row = (int*)p;

        const int nqb = (int)(M / 8);                       // 1024 quant blocks
        const int npb = N_TOT / 8;                          // 512 pack blocks
        prep_kernel<<<nqb + npb, 512, 0, stream>>>(
            (const float4*)x, (unsigned int*)xq, s_row, qsum_row,
            (const int4*)wq, (unsigned int*)w8, nqb);

        dim3 grid((unsigned)((M / 256) * (N_TOT / 256)));   // 512
        gemm256_i8_kernel<<<grid, 512, 0, stream>>>(
            xq, w8, s_row, qsum_row, sc, zp, bs, y);
    } else {
        dim3 grid(N_TOT / 32, (unsigned)(M / 32));
        fallback_kernel<<<grid, 256, 0, stream>>>(x, wq, zp, sc, bs, y);
    }
}